// Round 4
// baseline (272.250 us; speedup 1.0000x reference)
//
#include <hip/hip_runtime.h>

// out[n,m,:] = normalize(emb[m, g, :]),  g = gene_seq[n,m]
// N=256, M=2000, D=128. Output 262 MB fp32 -> write-BW bound, ~42 us floor.
//
// Measurement model (R3 post-mortem): bench dur_us includes ~207 us of
// harness poison fills (1.049 GB d_ws fill @165us + 262 MB d_out fill @42us
// dominate the rocprof top-5; our kernel never appears => kernel < 162 us).
// R1 kernel ~88 us, R3 ~64 us. Floor ~= 207 + 42 + ~4 = ~255 us total.
//
// R4: pre-normalize the entire table (8000 rows x 128) into d_ws in phase 1
// (4 MB, stays L2/L3-resident), so phase 2 is a pure 2-hop gather -> NT store
// with no per-element inv_norm load and no FMUL on the critical path.

#define N_SEQ   256
#define M_GENES 2000
#define D_DIM   128
#define ROWS    (M_GENES * 4)                 // 8000 table rows
#define P2_BX   25                            // phase-2 grid.x
#define P2_IT   10                            // 25*256*10 == 64000 exactly

typedef float vfloat4 __attribute__((ext_vector_type(4)));

__global__ __launch_bounds__(256) void normalize_table_kernel(
    const float* __restrict__ emb,            // (M,4,D)
    float*       __restrict__ table)          // (M*4, D) normalized, in d_ws
{
    const int idx = blockIdx.x * 256 + threadIdx.x;   // 0 .. 255999
    const int row = idx >> 5;                         // 0 .. 7999
    const int c   = idx & 31;
    const int off = (row << 7) + (c << 2);

    const vfloat4 v = *reinterpret_cast<const vfloat4*>(emb + off);
    float ss = v.x * v.x + v.y * v.y + v.z * v.z + v.w * v.w;
    ss += __shfl_xor(ss, 1, 32);
    ss += __shfl_xor(ss, 2, 32);
    ss += __shfl_xor(ss, 4, 32);
    ss += __shfl_xor(ss, 8, 32);
    ss += __shfl_xor(ss, 16, 32);
    const float inv = 1.0f / fmaxf(sqrtf(ss), 1e-12f);
    *reinterpret_cast<vfloat4*>(table + off) = v * inv;
}

__global__ __launch_bounds__(256) void gather_stream_kernel(
    const int*   __restrict__ gene_seq,       // (N,M)
    const float* __restrict__ table,          // (M*4, D) normalized
    float*       __restrict__ out)            // (N,M,D)
{
    const int n = blockIdx.y;
    const int* __restrict__ gs = gene_seq + n * M_GENES;
    float* __restrict__ outn = out + (size_t)n * (M_GENES * D_DIM);

    const int j0 = blockIdx.x * 256 + threadIdx.x;

    #pragma unroll
    for (int it = 0; it < P2_IT; ++it) {
        const int j = j0 + it * (P2_BX * 256);        // < 64000, exact cover
        const int m = j >> 5;
        const int c = j & 31;

        const int g = gs[m];                          // independent across it
        const vfloat4 v = *reinterpret_cast<const vfloat4*>(
            table + ((((m << 2) + g) << 7) + (c << 2)));
        __builtin_nontemporal_store(v, reinterpret_cast<vfloat4*>(outn + ((size_t)j << 2)));
    }
}

extern "C" void kernel_launch(void* const* d_in, const int* in_sizes, int n_in,
                              void* d_out, int out_size, void* d_ws, size_t ws_size,
                              hipStream_t stream) {
    const int*   gene_seq = (const int*)d_in[0];
    const float* emb      = (const float*)d_in[1];
    float*       out      = (float*)d_out;
    float*       table    = (float*)d_ws;             // 8000*128 floats = 4 MB

    // Phase 1: normalize all 8000 rows into d_ws (1000 blocks, ~4 us)
    normalize_table_kernel<<<dim3(ROWS * 32 / 256), dim3(256), 0, stream>>>(emb, table);

    // Phase 2: pure gather -> NT stream store, grid (25, 256), 10 float4/thread
    gather_stream_kernel<<<dim3(P2_BX, N_SEQ), dim3(256), 0, stream>>>(
        gene_seq, table, out);
}